// Round 7
// baseline (4539.329 us; speedup 1.0000x reference)
//
#include <hip/hip_runtime.h>
#include <float.h>
#include <math.h>

// Net_69664369541652: 8-iteration matching pursuit.
// One block per (b,t) position (2048 blocks, 512 threads). All per-position
// state (x_res, y_res, hmask) lives in LDS / registers across the 8
// iterations.
// Round 3: conv restructured into 3 shift-chunk passes (acc[28] live).
// Round 6: __launch_bounds__(512,4) -> (512,2). Round-5 counters showed the
// (512,4) bound clamped the kernel to 64 VGPRs and spilled ~80 live floats
// to scratch (WRITE_SIZE 192KB -> 174MB/dispatch, FETCH 3.5->15.3MB), and
// scratch backing limited occupancy to 45%. With a >=128-reg cap the 3-pass
// conv (~80-110 live) fits spill-free at 4 waves/SIMD.
// [Round 7: identical resubmit — round-6 bench hit GPUAcquisitionTimeout;
//  the (512,2) experiment is still unmeasured.]

#define NITER 8

__device__ __forceinline__ void argmaxStep(float &v, int &i, float v2, int i2) {
    // max with first-index (lower-index) tie break, matching jnp.argmax / top_k
    if (v2 > v || (v2 == v && i2 < i)) { v = v2; i = i2; }
}

// One conv pass over shifts [S0, S0+28). h[s,c] = sum_v encw[v,c]*yap[v+s].
// yap is zero outside [80,160), so v4 outside [V4LO,V4HI] contributes exact
// zeros and is skipped. Window W[i] = yap[v4+S0+i], i in [0,32); FMA uses
// W[k+s] (k<4, s<28 -> max index 30). yap max index = V4HI+S0+31 = 187 < 256.
template<int S0, int V4LO, int V4HI>
__device__ __forceinline__ void convPass(const float* __restrict__ wp,
                                         const float4* __restrict__ yap4,
                                         float bc, int lane, int wid,
                                         float* __restrict__ eparts)
{
    float acc[28];
    #pragma unroll
    for (int s = 0; s < 28; ++s) acc[s] = 0.f;

    #pragma unroll 2
    for (int v4 = V4LO; v4 <= V4HI; v4 += 4) {
        float wv0 = wp[(v4 + 0) * 512];
        float wv1 = wp[(v4 + 1) * 512];
        float wv2 = wp[(v4 + 2) * 512];
        float wv3 = wp[(v4 + 3) * 512];
        const float4* base = yap4 + ((v4 + S0) >> 2);
        float W[32];
        #pragma unroll
        for (int q = 0; q < 8; ++q) {
            float4 t = base[q];
            W[4 * q + 0] = t.x; W[4 * q + 1] = t.y;
            W[4 * q + 2] = t.z; W[4 * q + 3] = t.w;
        }
        #pragma unroll
        for (int s = 0; s < 28; ++s) {
            acc[s] += wv0 * W[s + 0];
            acc[s] += wv1 * W[s + 1];
            acc[s] += wv2 * W[s + 2];
            acc[s] += wv3 * W[s + 3];
        }
    }

    // energy partials: e[s] = sum_c (h[s,c])^2, wave-level partial per wid
    #pragma unroll
    for (int s = 0; s < 28; ++s) {
        if (S0 + s < 81) {
            float h = acc[s] + bc;
            float e = h * h;
            #pragma unroll
            for (int off = 32; off; off >>= 1) e += __shfl_xor(e, off);
            if (lane == 0) eparts[(S0 + s) * 8 + wid] = e;
        }
    }
}

__global__ __launch_bounds__(512, 2)
void mp_kernel(const float* __restrict__ x, const float* __restrict__ y,
               const float* __restrict__ encw, const float* __restrict__ encb,
               const float* __restrict__ decw, const float* __restrict__ decb,
               double* __restrict__ lossSum, int* __restrict__ nzCount)
{
    const int tid  = threadIdx.x;
    const int bt   = blockIdx.x;
    const int lane = tid & 63;
    const int wid  = tid >> 6;
    const int c    = tid;            // encoder channel owned by this thread

    __shared__ __align__(16) float yap[256];   // zero-padded y_align_attn: yap[80+j]=ya[j]
    __shared__ float xr[80], yr[80], yy[80];   // x_res, y_res, original y
    __shared__ __align__(16) float hrow[512];  // selected h row (after prev-mask zeroing)
    __shared__ float xext[160];
    __shared__ float eparts[81 * 8];
    __shared__ float selVal[64];
    __shared__ int   selIdx[64];
    __shared__ float rv[8];
    __shared__ int   ri[8];
    __shared__ int   cnt;
    __shared__ int   theta_s, hind_s;
    __shared__ float ysq_s, bf1, bf2;

    float myy = 0.f;
    if (tid < 80) {
        xr[tid] = x[bt * 80 + tid];
        myy = y[bt * 80 + tid];
        yr[tid] = myy;
        yy[tid] = myy;
    }
    if (tid < 256) yap[tid] = 0.f;

    // global nonzero count of y (denominator of seq_loss), once
    {
        unsigned long long b = __ballot(tid < 80 && myy != 0.0f);
        if (lane == 0 && wid < 2) {
            int n = (int)__popcll(b);
            if (n) atomicAdd(nzCount, n);
        }
    }

    const float bc = encb[c];
    bool   mprev = false;       // hmask (mask_prev) bit for channel c
    double blockLoss = 0.0;     // accumulated by thread 0 only

    for (int iter = 0; iter < NITER; ++iter) {
        __syncthreads();

        // ---------- ||y_res||^2 ----------
        {
            float v = 0.f;
            if (tid < 80) { float t = yr[tid]; v = t * t; }
            #pragma unroll
            for (int off = 32; off; off >>= 1) v += __shfl_xor(v, off);
            if (lane == 0) rv[wid] = v;
            __syncthreads();
            if (tid == 0) {
                float s = 0.f;
                for (int k = 0; k < 8; ++k) s += rv[k];
                ysq_s = s;
            }
            __syncthreads();
        }

        // ---------- selector: cosine sim over 159 shifts, argmax ----------
        {
            float sv = -FLT_MAX; int si = 0x7fffffff;
            if (tid < 159) {
                int s = tid;
                int jlo = (s - 79 > 0) ? s - 79 : 0;
                int jhi = (s + 1 < 80) ? s + 1 : 80;
                float num = 0.f, wn = 0.f;
                for (int j = jlo; j < jhi; ++j) {
                    float xv = xr[j];
                    num += xv * yr[j + 79 - s];
                    wn  += xv * xv;
                }
                float den = sqrtf(ysq_s) * sqrtf(wn);
                sv = (den == 0.f) ? 0.f : num / den;   // where(denom==0, 0, num/denom)
                si = s;
            }
            #pragma unroll
            for (int off = 32; off; off >>= 1) {
                float v2 = __shfl_xor(sv, off);
                int   i2 = __shfl_xor(si, off);
                argmaxStep(sv, si, v2, i2);
            }
            if (lane == 0) { rv[wid] = sv; ri[wid] = si; }
            __syncthreads();
            if (tid == 0) {
                float bv = rv[0]; int bi = ri[0];
                for (int k = 1; k < 8; ++k) argmaxStep(bv, bi, rv[k], ri[k]);
                theta_s = bi;
            }
            __syncthreads();
        }
        const int theta = theta_s;

        // ---------- softmax attention -> y_align_attn into yap[80..160) ----------
        float yao = 0.f, z = -FLT_MAX;
        if (tid < 80) {
            int j = theta + tid - 79;                  // x_aug[theta, d]
            if (j >= 0 && j < 80) yao = xr[j];
            z = yao * yy[tid];                         // TEMPER = 1
        }
        {
            float zm = z;
            #pragma unroll
            for (int off = 32; off; off >>= 1) zm = fmaxf(zm, __shfl_xor(zm, off));
            if (lane == 0) rv[wid] = zm;
            __syncthreads();
            if (tid == 0) {
                float m = rv[0];
                for (int k = 1; k < 8; ++k) m = fmaxf(m, rv[k]);
                bf1 = m;
            }
            __syncthreads();
        }
        float ez = 0.f;
        if (tid < 80) ez = expf(z - bf1);
        {
            float es = ez;
            #pragma unroll
            for (int off = 32; off; off >>= 1) es += __shfl_xor(es, off);
            if (lane == 0) rv[wid] = es;
            __syncthreads();
            if (tid == 0) {
                float s = 0.f;
                for (int k = 0; k < 8; ++k) s += rv[k];
                bf2 = s;
            }
            __syncthreads();
        }
        if (tid < 80) yap[80 + tid] = yao * (ez / bf2);
        __syncthreads();

        // ---------- encoder conv, 3 shift-chunk passes (28 acc live each) ----
        {
            const float* wp = encw + c;
            const float4* yap4 = (const float4*)yap;
            convPass< 0, 52, 156>(wp, yap4, bc, lane, wid, eparts);
            convPass<28, 24, 128>(wp, yap4, bc, lane, wid, eparts);
            convPass<56,  0, 100>(wp, yap4, bc, lane, wid, eparts);
        }
        __syncthreads();

        // ---------- energy pooling argmax over 81 shifts ----------
        {
            float ev = -FLT_MAX; int ei = 0x7fffffff;
            if (tid < 81) {
                float e = 0.f;
                #pragma unroll
                for (int k = 0; k < 8; ++k) e += eparts[tid * 8 + k];
                ev = e; ei = tid;
            }
            #pragma unroll
            for (int off = 32; off; off >>= 1) {
                float v2 = __shfl_xor(ev, off);
                int   i2 = __shfl_xor(ei, off);
                argmaxStep(ev, ei, v2, i2);
            }
            if (lane == 0) { rv[wid] = ev; ri[wid] = ei; }
            __syncthreads();
            if (tid == 0) {
                float bv = rv[0]; int bi = ri[0];
                for (int k = 1; k < 8; ++k) argmaxStep(bv, bi, rv[k], ri[k]);
                hind_s = bi;
            }
            __syncthreads();
        }
        const int hind = hind_s;

        // ---------- recompute h[hind, c] (80 FMAs; replaces keeping 88 acc) --
        float hv = bc;
        {
            const float* wp = encw + c;
            #pragma unroll 4
            for (int v = 80 - hind; v < 160 - hind; ++v)
                hv += wp[v * 512] * yap[v + hind];
        }
        if (iter > 0 && mprev) hv = 0.f;   // h = where(mask_prev>0, 0, h)
        hrow[c] = hv;
        if (tid == 0) cnt = 0;
        __syncthreads();

        // ---------- exact top-64 by rank count ----------
        {
            const float k0 = hv * hv;
            int rank = 0;
            const float4* h4 = (const float4*)hrow;
            for (int q = 0; q < 128; ++q) {
                float4 hq = h4[q];
                int cb = q * 4;
                float ka = hq.x * hq.x, kb = hq.y * hq.y;
                float kc = hq.z * hq.z, kd = hq.w * hq.w;
                rank += (ka > k0) || (ka == k0 && (cb + 0) < c);
                rank += (kb > k0) || (kb == k0 && (cb + 1) < c);
                rank += (kc > k0) || (kc == k0 && (cb + 2) < c);
                rank += (kd > k0) || (kd == k0 && (cb + 3) < c);
            }
            bool sel = rank < 64;          // exact lax.top_k tie semantics
            mprev = mprev || sel;          // mask_prev accumulation (>0 test only)
            if (sel) {
                int p = atomicAdd(&cnt, 1);
                selIdx[p] = c;
                selVal[p] = hv;            // h = where(mask_cur>0, h, 0): only kept ones
            }
        }
        __syncthreads();

        // ---------- sparse decoder: x_ext = h_sel @ dec_w + dec_b ----------
        if (tid < 160) {
            float a2 = decb[tid];
            for (int k = 0; k < 64; ++k)
                a2 += selVal[k] * decw[selIdx[k] * 160 + tid];
            xext[tid] = a2;
        }
        __syncthreads();

        // ---------- y_ele gather, loss, residual updates ----------
        float ye = 0.f, yrv = 0.f, lp = 0.f;
        if (tid < 80) {
            ye  = xext[80 - hind + tid];       // offs = 80 - h_ind + i
            yrv = yr[tid];
            float d = ye - yrv;
            lp = (yy[tid] == 0.0f) ? 0.f : d * d;   // seq_mask = (y == 0)
        }
        {
            float ls = lp;
            #pragma unroll
            for (int off = 32; off; off >>= 1) ls += __shfl_xor(ls, off);
            if (lane == 0) rv[wid] = ls;
            __syncthreads();
            if (tid == 0) {
                float s = 0.f;
                for (int k = 0; k < 8; ++k) s += rv[k];
                blockLoss += (double)s;
            }
        }
        float xe = 0.f;
        if (tid < 80) xe = yap[tid + 159 - theta];  // x_ele via zero-padded yap
        __syncthreads();
        if (tid < 80) {
            yr[tid] = yrv - ye;     // y_res -= y_ele
            xr[tid] -= xe;          // x_res -= x_ele
        }
    }

    if (tid == 0) atomicAdd(lossSum, blockLoss);
}

__global__ void finish_kernel(const double* __restrict__ lossSum,
                              const int* __restrict__ nz,
                              float* __restrict__ out)
{
    int n = *nz;
    if (n < 1) n = 1;
    out[0] = (float)(*lossSum / (8.0 * (double)n));
}

extern "C" void kernel_launch(void* const* d_in, const int* in_sizes, int n_in,
                              void* d_out, int out_size, void* d_ws, size_t ws_size,
                              hipStream_t stream) {
    (void)in_sizes; (void)n_in; (void)out_size; (void)ws_size;
    const float* x    = (const float*)d_in[0];
    const float* y    = (const float*)d_in[1];
    const float* encw = (const float*)d_in[2];
    const float* encb = (const float*)d_in[3];
    const float* decw = (const float*)d_in[4];
    const float* decb = (const float*)d_in[5];

    double* lossSum = (double*)d_ws;
    int*    nz      = (int*)((char*)d_ws + 8);

    hipMemsetAsync(d_ws, 0, 16, stream);
    mp_kernel<<<2048, 512, 0, stream>>>(x, y, encw, encb, decw, decb, lossSum, nz);
    finish_kernel<<<1, 1, 0, stream>>>(lossSum, nz, (float*)d_out);
}

// Round 8
// 3295.887 us; speedup vs baseline: 1.3773x; 1.3773x over previous
//
#include <hip/hip_runtime.h>
#include <float.h>
#include <math.h>

// Net_69664369541652: 8-iteration matching pursuit.
// One block per (b,t) position (2048 blocks, 512 threads).
// Round 8: register-diet conv. Rounds 2/5/7 triangulated the bottleneck:
// the conv's ~90-110 live floats either spill to scratch (64-reg clamp,
// r5: WRITE_SIZE 174MB) or overflow into AGPRs (relaxed bound, r7: VGPR=84
// but 1 block/CU => hidden AGPR allocation on the unified file). Fix the
// structure, not the bound: 7 passes x 12 shifts, acc[12] + 16-float window
// (4x ds_read_b128) + 4 weights ~= 50 live regs < 64. Also 11% fewer FMAs
// (7968 vs 8960 per thread-iter). launch_bounds(512,4) = 64-reg budget,
// now spill-free.

#define NITER 8

__device__ __forceinline__ void argmaxStep(float &v, int &i, float v2, int i2) {
    // max with first-index (lower-index) tie break, matching jnp.argmax / top_k
    if (v2 > v || (v2 == v && i2 < i)) { v = v2; i = i2; }
}

// Conv pass over shifts [S0, S0+12). h[s,c] = sum_v encw[v,c]*yap[v+s].
// yap zero outside [80,160): v4 outside [V4LO,V4HI] contributes exact 0s.
// Per iter: 4 weight loads, 4 ds_read_b128 (W[0..15], uses W[0..14]),
// 48 static-index FMAs. Bounds verified: taps needed [max(0,69-S0),159-S0]
// subset of [V4LO, V4HI+3]; yap index max = V4HI+S0+15 = 171 < 256.
template<int S0, int V4LO, int V4HI>
__device__ __forceinline__ void convPass(const float* __restrict__ wp,
                                         const float4* __restrict__ yap4,
                                         float bc, int lane, int wid,
                                         float* __restrict__ eparts)
{
    float acc[12];
    #pragma unroll
    for (int s = 0; s < 12; ++s) acc[s] = 0.f;

    #pragma unroll 2
    for (int v4 = V4LO; v4 <= V4HI; v4 += 4) {
        float wv0 = wp[(v4 + 0) * 512];
        float wv1 = wp[(v4 + 1) * 512];
        float wv2 = wp[(v4 + 2) * 512];
        float wv3 = wp[(v4 + 3) * 512];
        const float4* base = yap4 + ((v4 + S0) >> 2);
        float4 A = base[0], B = base[1], C = base[2], D = base[3];
        float W[16] = {A.x, A.y, A.z, A.w, B.x, B.y, B.z, B.w,
                       C.x, C.y, C.z, C.w, D.x, D.y, D.z, D.w};
        #pragma unroll
        for (int s = 0; s < 12; ++s) {
            acc[s] += wv0 * W[s + 0];
            acc[s] += wv1 * W[s + 1];
            acc[s] += wv2 * W[s + 2];
            acc[s] += wv3 * W[s + 3];
        }
    }

    // energy partials: e[s] = sum_c (h[s,c])^2, wave-level partial per wid
    #pragma unroll
    for (int s = 0; s < 12; ++s) {
        if (S0 + s < 81) {
            float h = acc[s] + bc;
            float e = h * h;
            #pragma unroll
            for (int off = 32; off; off >>= 1) e += __shfl_xor(e, off);
            if (lane == 0) eparts[(S0 + s) * 8 + wid] = e;
        }
    }
}

__global__ __launch_bounds__(512, 4)
void mp_kernel(const float* __restrict__ x, const float* __restrict__ y,
               const float* __restrict__ encw, const float* __restrict__ encb,
               const float* __restrict__ decw, const float* __restrict__ decb,
               double* __restrict__ lossSum, int* __restrict__ nzCount)
{
    const int tid  = threadIdx.x;
    const int bt   = blockIdx.x;
    const int lane = tid & 63;
    const int wid  = tid >> 6;
    const int c    = tid;            // encoder channel owned by this thread

    __shared__ __align__(16) float yap[256];   // zero-padded y_align_attn: yap[80+j]=ya[j]
    __shared__ float xr[80], yr[80], yy[80];   // x_res, y_res, original y
    __shared__ __align__(16) float hrow[512];  // selected h row (after prev-mask zeroing)
    __shared__ float xext[160];
    __shared__ float eparts[81 * 8];
    __shared__ float selVal[64];
    __shared__ int   selIdx[64];
    __shared__ float rv[8];
    __shared__ int   ri[8];
    __shared__ int   cnt;
    __shared__ int   theta_s, hind_s;
    __shared__ float ysq_s, bf1, bf2;

    float myy = 0.f;
    if (tid < 80) {
        xr[tid] = x[bt * 80 + tid];
        myy = y[bt * 80 + tid];
        yr[tid] = myy;
        yy[tid] = myy;
    }
    if (tid < 256) yap[tid] = 0.f;

    // global nonzero count of y (denominator of seq_loss), once
    {
        unsigned long long b = __ballot(tid < 80 && myy != 0.0f);
        if (lane == 0 && wid < 2) {
            int n = (int)__popcll(b);
            if (n) atomicAdd(nzCount, n);
        }
    }

    const float bc = encb[c];
    bool   mprev = false;       // hmask (mask_prev) bit for channel c
    double blockLoss = 0.0;     // accumulated by thread 0 only

    for (int iter = 0; iter < NITER; ++iter) {
        __syncthreads();

        // ---------- ||y_res||^2 ----------
        {
            float v = 0.f;
            if (tid < 80) { float t = yr[tid]; v = t * t; }
            #pragma unroll
            for (int off = 32; off; off >>= 1) v += __shfl_xor(v, off);
            if (lane == 0) rv[wid] = v;
            __syncthreads();
            if (tid == 0) {
                float s = 0.f;
                for (int k = 0; k < 8; ++k) s += rv[k];
                ysq_s = s;
            }
            __syncthreads();
        }

        // ---------- selector: cosine sim over 159 shifts, argmax ----------
        {
            float sv = -FLT_MAX; int si = 0x7fffffff;
            if (tid < 159) {
                int s = tid;
                int jlo = (s - 79 > 0) ? s - 79 : 0;
                int jhi = (s + 1 < 80) ? s + 1 : 80;
                float num = 0.f, wn = 0.f;
                for (int j = jlo; j < jhi; ++j) {
                    float xv = xr[j];
                    num += xv * yr[j + 79 - s];
                    wn  += xv * xv;
                }
                float den = sqrtf(ysq_s) * sqrtf(wn);
                sv = (den == 0.f) ? 0.f : num / den;   // where(denom==0, 0, num/denom)
                si = s;
            }
            #pragma unroll
            for (int off = 32; off; off >>= 1) {
                float v2 = __shfl_xor(sv, off);
                int   i2 = __shfl_xor(si, off);
                argmaxStep(sv, si, v2, i2);
            }
            if (lane == 0) { rv[wid] = sv; ri[wid] = si; }
            __syncthreads();
            if (tid == 0) {
                float bv = rv[0]; int bi = ri[0];
                for (int k = 1; k < 8; ++k) argmaxStep(bv, bi, rv[k], ri[k]);
                theta_s = bi;
            }
            __syncthreads();
        }
        const int theta = theta_s;

        // ---------- softmax attention -> y_align_attn into yap[80..160) ----------
        float yao = 0.f, z = -FLT_MAX;
        if (tid < 80) {
            int j = theta + tid - 79;                  // x_aug[theta, d]
            if (j >= 0 && j < 80) yao = xr[j];
            z = yao * yy[tid];                         // TEMPER = 1
        }
        {
            float zm = z;
            #pragma unroll
            for (int off = 32; off; off >>= 1) zm = fmaxf(zm, __shfl_xor(zm, off));
            if (lane == 0) rv[wid] = zm;
            __syncthreads();
            if (tid == 0) {
                float m = rv[0];
                for (int k = 1; k < 8; ++k) m = fmaxf(m, rv[k]);
                bf1 = m;
            }
            __syncthreads();
        }
        float ez = 0.f;
        if (tid < 80) ez = expf(z - bf1);
        {
            float es = ez;
            #pragma unroll
            for (int off = 32; off; off >>= 1) es += __shfl_xor(es, off);
            if (lane == 0) rv[wid] = es;
            __syncthreads();
            if (tid == 0) {
                float s = 0.f;
                for (int k = 0; k < 8; ++k) s += rv[k];
                bf2 = s;
            }
            __syncthreads();
        }
        if (tid < 80) yap[80 + tid] = yao * (ez / bf2);
        __syncthreads();

        // ---------- encoder conv, 7 passes x 12 shifts (register diet) ------
        {
            const float* wp = encw + c;
            const float4* yap4 = (const float4*)yap;
            convPass< 0, 64, 156>(wp, yap4, bc, lane, wid, eparts);
            convPass<12, 52, 144>(wp, yap4, bc, lane, wid, eparts);
            convPass<24, 40, 132>(wp, yap4, bc, lane, wid, eparts);
            convPass<36, 28, 120>(wp, yap4, bc, lane, wid, eparts);
            convPass<48, 16, 108>(wp, yap4, bc, lane, wid, eparts);
            convPass<60,  4,  96>(wp, yap4, bc, lane, wid, eparts);
            convPass<72,  0,  84>(wp, yap4, bc, lane, wid, eparts);
        }
        __syncthreads();

        // ---------- energy pooling argmax over 81 shifts ----------
        {
            float ev = -FLT_MAX; int ei = 0x7fffffff;
            if (tid < 81) {
                float e = 0.f;
                #pragma unroll
                for (int k = 0; k < 8; ++k) e += eparts[tid * 8 + k];
                ev = e; ei = tid;
            }
            #pragma unroll
            for (int off = 32; off; off >>= 1) {
                float v2 = __shfl_xor(ev, off);
                int   i2 = __shfl_xor(ei, off);
                argmaxStep(ev, ei, v2, i2);
            }
            if (lane == 0) { rv[wid] = ev; ri[wid] = ei; }
            __syncthreads();
            if (tid == 0) {
                float bv = rv[0]; int bi = ri[0];
                for (int k = 1; k < 8; ++k) argmaxStep(bv, bi, rv[k], ri[k]);
                hind_s = bi;
            }
            __syncthreads();
        }
        const int hind = hind_s;

        // ---------- recompute h[hind, c] (80 FMAs) ----------
        float hv = bc;
        {
            const float* wp = encw + c;
            #pragma unroll 4
            for (int v = 80 - hind; v < 160 - hind; ++v)
                hv += wp[v * 512] * yap[v + hind];
        }
        if (iter > 0 && mprev) hv = 0.f;   // h = where(mask_prev>0, 0, h)
        hrow[c] = hv;
        if (tid == 0) cnt = 0;
        __syncthreads();

        // ---------- exact top-64 by rank count ----------
        {
            const float k0 = hv * hv;
            int rank = 0;
            const float4* h4 = (const float4*)hrow;
            for (int q = 0; q < 128; ++q) {
                float4 hq = h4[q];
                int cb = q * 4;
                float ka = hq.x * hq.x, kb = hq.y * hq.y;
                float kc = hq.z * hq.z, kd = hq.w * hq.w;
                rank += (ka > k0) || (ka == k0 && (cb + 0) < c);
                rank += (kb > k0) || (kb == k0 && (cb + 1) < c);
                rank += (kc > k0) || (kc == k0 && (cb + 2) < c);
                rank += (kd > k0) || (kd == k0 && (cb + 3) < c);
            }
            bool sel = rank < 64;          // exact lax.top_k tie semantics
            mprev = mprev || sel;          // mask_prev accumulation (>0 test only)
            if (sel) {
                int p = atomicAdd(&cnt, 1);
                selIdx[p] = c;
                selVal[p] = hv;            // h = where(mask_cur>0, h, 0): only kept ones
            }
        }
        __syncthreads();

        // ---------- sparse decoder: x_ext = h_sel @ dec_w + dec_b ----------
        if (tid < 160) {
            float a2 = decb[tid];
            for (int k = 0; k < 64; ++k)
                a2 += selVal[k] * decw[selIdx[k] * 160 + tid];
            xext[tid] = a2;
        }
        __syncthreads();

        // ---------- y_ele gather, loss, residual updates ----------
        float ye = 0.f, yrv = 0.f, lp = 0.f;
        if (tid < 80) {
            ye  = xext[80 - hind + tid];       // offs = 80 - h_ind + i
            yrv = yr[tid];
            float d = ye - yrv;
            lp = (yy[tid] == 0.0f) ? 0.f : d * d;   // seq_mask = (y == 0)
        }
        {
            float ls = lp;
            #pragma unroll
            for (int off = 32; off; off >>= 1) ls += __shfl_xor(ls, off);
            if (lane == 0) rv[wid] = ls;
            __syncthreads();
            if (tid == 0) {
                float s = 0.f;
                for (int k = 0; k < 8; ++k) s += rv[k];
                blockLoss += (double)s;
            }
        }
        float xe = 0.f;
        if (tid < 80) xe = yap[tid + 159 - theta];  // x_ele via zero-padded yap
        __syncthreads();
        if (tid < 80) {
            yr[tid] = yrv - ye;     // y_res -= y_ele
            xr[tid] -= xe;          // x_res -= x_ele
        }
    }

    if (tid == 0) atomicAdd(lossSum, blockLoss);
}

__global__ void finish_kernel(const double* __restrict__ lossSum,
                              const int* __restrict__ nz,
                              float* __restrict__ out)
{
    int n = *nz;
    if (n < 1) n = 1;
    out[0] = (float)(*lossSum / (8.0 * (double)n));
}

extern "C" void kernel_launch(void* const* d_in, const int* in_sizes, int n_in,
                              void* d_out, int out_size, void* d_ws, size_t ws_size,
                              hipStream_t stream) {
    (void)in_sizes; (void)n_in; (void)out_size; (void)ws_size;
    const float* x    = (const float*)d_in[0];
    const float* y    = (const float*)d_in[1];
    const float* encw = (const float*)d_in[2];
    const float* encb = (const float*)d_in[3];
    const float* decw = (const float*)d_in[4];
    const float* decb = (const float*)d_in[5];

    double* lossSum = (double*)d_ws;
    int*    nz      = (int*)((char*)d_ws + 8);

    hipMemsetAsync(d_ws, 0, 16, stream);
    mp_kernel<<<2048, 512, 0, stream>>>(x, y, encw, encb, decw, decb, lossSum, nz);
    finish_kernel<<<1, 1, 0, stream>>>(lossSum, nz, (float*)d_out);
}

// Round 14
// 2698.719 us; speedup vs baseline: 1.6820x; 1.2213x over previous
//
#include <hip/hip_runtime.h>
#include <float.h>
#include <math.h>

// Net_69664369541652: 8-iteration matching pursuit.
// One block per (b,t) position (2048 blocks, 512 threads).
// Round 9: MFMA conv. Rounds 2-8 showed the fp32 VALU conv is structurally
// capped ~2.5-3ms (2.4x instruction inflation, occupancy cliffs). The conv
// is a GEMM H(81x512) = Y(81x160) @ W(160x512); move it to
// mfma_f32_16x16x32_bf16 with bf16x3 split precision (hi/lo, Markidis):
// h rel err ~1e-5 -> energy-argmax flip prob ~1e-3/decision, loss impact
// ~2e-3 << 2e-2 threshold. h VALUES used downstream (top-64, decoder) stay
// fp32-exact via the 80-FMA recompute. A-frags: parity-duplicated bf16 yap
// copies in LDS -> any 8-elem window = 4 aligned ds_read_b32 with correct
// reg packing. B-frags: prep kernel pre-splits encw into whi/wlo[c][w]
// (bf16, c-major) in d_ws -> 16B contiguous loads.
// [Rounds 10-14: identical resubmits — infra timeouts; still unmeasured.]

#define NITER 8

typedef float f32x4 __attribute__((ext_vector_type(4)));
typedef short s16x8 __attribute__((ext_vector_type(8)));

union U16B { uint4 u4; unsigned int u[4]; s16x8 v; };

__device__ __forceinline__ unsigned short f2bf(float f) {
    unsigned int u = __float_as_uint(f);
    unsigned int r = (u + 0x7FFFu + ((u >> 16) & 1u)) >> 16;   // RNE
    return (unsigned short)r;
}
__device__ __forceinline__ float bf2f(unsigned short h) {
    return __uint_as_float(((unsigned int)h) << 16);
}

__device__ __forceinline__ void argmaxStep(float &v, int &i, float v2, int i2) {
    if (v2 > v || (v2 == v && i2 < i)) { v = v2; i = i2; }
}

// Prep: encw (w-major f32 [160][512]) -> whi/wlo (bf16 hi/lo, c-major [512][160])
__global__ void prep_kernel(const float* __restrict__ encw,
                            unsigned short* __restrict__ whi,
                            unsigned short* __restrict__ wlo)
{
    int o = blockIdx.x * 256 + threadIdx.x;      // 81920 total
    if (o >= 512 * 160) return;
    int c = o / 160, w = o % 160;
    float f = encw[w * 512 + c];
    unsigned short h = f2bf(f);
    unsigned short l = f2bf(f - bf2f(h));
    whi[o] = h;
    wlo[o] = l;
}

__global__ __launch_bounds__(512, 2)
void mp_kernel(const float* __restrict__ x, const float* __restrict__ y,
               const float* __restrict__ encw, const float* __restrict__ encb,
               const float* __restrict__ decw, const float* __restrict__ decb,
               const unsigned short* __restrict__ whi,
               const unsigned short* __restrict__ wlo,
               double* __restrict__ lossSum, int* __restrict__ nzCount)
{
    const int tid  = threadIdx.x;
    const int bt   = blockIdx.x;
    const int lane = tid & 63;
    const int wid  = tid >> 6;
    const int c    = tid;            // encoder channel owned by this thread
    const int lg   = lane >> 4;      // k-block / D-row group
    const int li   = lane & 15;      // A-row (s) / B-col (c) within tile

    __shared__ __align__(16) float yap[256];   // zero-padded y_align_attn (fp32)
    // parity-duplicated bf16 copies of yap: E[i]=yap[i], O[i]=yap[i+1]
    __shared__ __align__(16) unsigned int yEhi32[128], yElo32[128];
    __shared__ __align__(16) unsigned int yOhi32[128], yOlo32[128];
    __shared__ float xr[80], yr[80], yy[80];
    __shared__ __align__(16) float hrow[512];
    __shared__ float xext[160];
    __shared__ float eparts[96 * 8];           // energy partials [s][wave]
    __shared__ float selVal[64];
    __shared__ int   selIdx[64];
    __shared__ float rv[8];
    __shared__ int   ri[8];
    __shared__ int   cnt;
    __shared__ int   theta_s, hind_s;
    __shared__ float ysq_s, bf1, bf2;

    float myy = 0.f;
    if (tid < 80) {
        xr[tid] = x[bt * 80 + tid];
        myy = y[bt * 80 + tid];
        yr[tid] = myy;
        yy[tid] = myy;
    }
    if (tid < 256) yap[tid] = 0.f;
    if (tid < 128) { yEhi32[tid] = 0; yElo32[tid] = 0; yOhi32[tid] = 0; yOlo32[tid] = 0; }

    // global nonzero count of y (denominator of seq_loss), once
    {
        unsigned long long b = __ballot(tid < 80 && myy != 0.0f);
        if (lane == 0 && wid < 2) {
            int n = (int)__popcll(b);
            if (n) atomicAdd(nzCount, n);
        }
    }

    const float bc = encb[c];                  // for fp32 h-recompute
    float bcv[4];                              // bias for MFMA energy cols
    #pragma unroll
    for (int ct = 0; ct < 4; ++ct) bcv[ct] = encb[((wid * 4 + ct) << 4) + li];

    bool   mprev = false;
    double blockLoss = 0.0;

    for (int iter = 0; iter < NITER; ++iter) {
        __syncthreads();

        // ---------- ||y_res||^2 ----------
        {
            float v = 0.f;
            if (tid < 80) { float t = yr[tid]; v = t * t; }
            #pragma unroll
            for (int off = 32; off; off >>= 1) v += __shfl_xor(v, off);
            if (lane == 0) rv[wid] = v;
            __syncthreads();
            if (tid == 0) {
                float s = 0.f;
                for (int k = 0; k < 8; ++k) s += rv[k];
                ysq_s = s;
            }
            __syncthreads();
        }

        // ---------- selector: cosine sim over 159 shifts, argmax ----------
        {
            float sv = -FLT_MAX; int si = 0x7fffffff;
            if (tid < 159) {
                int s = tid;
                int jlo = (s - 79 > 0) ? s - 79 : 0;
                int jhi = (s + 1 < 80) ? s + 1 : 80;
                float num = 0.f, wn = 0.f;
                for (int j = jlo; j < jhi; ++j) {
                    float xv = xr[j];
                    num += xv * yr[j + 79 - s];
                    wn  += xv * xv;
                }
                float den = sqrtf(ysq_s) * sqrtf(wn);
                sv = (den == 0.f) ? 0.f : num / den;
                si = s;
            }
            #pragma unroll
            for (int off = 32; off; off >>= 1) {
                float v2 = __shfl_xor(sv, off);
                int   i2 = __shfl_xor(si, off);
                argmaxStep(sv, si, v2, i2);
            }
            if (lane == 0) { rv[wid] = sv; ri[wid] = si; }
            __syncthreads();
            if (tid == 0) {
                float bv = rv[0]; int bi = ri[0];
                for (int k = 1; k < 8; ++k) argmaxStep(bv, bi, rv[k], ri[k]);
                theta_s = bi;
            }
            __syncthreads();
        }
        const int theta = theta_s;

        // ---------- softmax attention -> y_align_attn into yap[80..160) ------
        float yao = 0.f, z = -FLT_MAX;
        if (tid < 80) {
            int j = theta + tid - 79;
            if (j >= 0 && j < 80) yao = xr[j];
            z = yao * yy[tid];
        }
        {
            float zm = z;
            #pragma unroll
            for (int off = 32; off; off >>= 1) zm = fmaxf(zm, __shfl_xor(zm, off));
            if (lane == 0) rv[wid] = zm;
            __syncthreads();
            if (tid == 0) {
                float m = rv[0];
                for (int k = 1; k < 8; ++k) m = fmaxf(m, rv[k]);
                bf1 = m;
            }
            __syncthreads();
        }
        float ez = 0.f;
        if (tid < 80) ez = expf(z - bf1);
        {
            float es = ez;
            #pragma unroll
            for (int off = 32; off; off >>= 1) es += __shfl_xor(es, off);
            if (lane == 0) rv[wid] = es;
            __syncthreads();
            if (tid == 0) {
                float s = 0.f;
                for (int k = 0; k < 8; ++k) s += rv[k];
                bf2 = s;
            }
            __syncthreads();
        }
        if (tid < 80) yap[80 + tid] = yao * (ez / bf2);
        __syncthreads();

        // ---------- rebuild bf16 hi/lo parity copies of yap ----------
        if (tid >= 78 && tid < 160) {
            float f0 = yap[tid];
            float f1 = yap[tid + 1];
            unsigned short h0 = f2bf(f0), h1 = f2bf(f1);
            unsigned short l0 = f2bf(f0 - bf2f(h0)), l1 = f2bf(f1 - bf2f(h1));
            ((unsigned short*)yEhi32)[tid] = h0;
            ((unsigned short*)yElo32)[tid] = l0;
            ((unsigned short*)yOhi32)[tid] = h1;
            ((unsigned short*)yOlo32)[tid] = l1;
        }
        __syncthreads();

        // ---------- encoder conv via MFMA (bf16x3) + energy partials --------
        // H = Y*W: A[s,k]=yap[k+s] (M=96 in 6 tiles), B[k,c] (N=512, wave owns
        // 4 c-tiles), K=160 in 5 steps of 32. D: col=li (c), row=lg*4+r (s).
        {
            const unsigned int* yH = (lane & 1) ? yOhi32 : yEhi32;
            const unsigned int* yL = (lane & 1) ? yOlo32 : yElo32;
            const int dwl = (lg << 2) + (li >> 1);   // lane-local dword offset

            for (int m = 0; m < 6; ++m) {
                // A-fragments for all 5 k-steps (hi+lo): window start
                // p = m*16 + t*32 + lg*8 + li; dword = p>>1; parity-matched copy.
                s16x8 Ah[5], Al[5];
                #pragma unroll
                for (int t = 0; t < 5; ++t) {
                    int dw = m * 8 + t * 16 + dwl;
                    U16B a, b;
                    a.u[0] = yH[dw];     a.u[1] = yH[dw + 1];
                    a.u[2] = yH[dw + 2]; a.u[3] = yH[dw + 3];
                    b.u[0] = yL[dw];     b.u[1] = yL[dw + 1];
                    b.u[2] = yL[dw + 2]; b.u[3] = yL[dw + 3];
                    Ah[t] = a.v;
                    Al[t] = b.v;
                }
                float ep0 = 0.f, ep1 = 0.f, ep2 = 0.f, ep3 = 0.f;
                #pragma unroll
                for (int ct = 0; ct < 4; ++ct) {
                    const unsigned short* wh = whi + (((wid * 4 + ct) << 4) + li) * 160;
                    const unsigned short* wl = wlo + (((wid * 4 + ct) << 4) + li) * 160;
                    f32x4 acc = {0.f, 0.f, 0.f, 0.f};
                    #pragma unroll
                    for (int t = 0; t < 5; ++t) {
                        U16B bh, bl;
                        bh.u4 = *(const uint4*)(wh + (t << 5) + (lg << 3));
                        bl.u4 = *(const uint4*)(wl + (t << 5) + (lg << 3));
                        acc = __builtin_amdgcn_mfma_f32_16x16x32_bf16(Ah[t], bh.v, acc, 0, 0, 0);
                        acc = __builtin_amdgcn_mfma_f32_16x16x32_bf16(Ah[t], bl.v, acc, 0, 0, 0);
                        acc = __builtin_amdgcn_mfma_f32_16x16x32_bf16(Al[t], bh.v, acc, 0, 0, 0);
                    }
                    float b0 = bcv[ct];
                    float h0 = acc[0] + b0, h1 = acc[1] + b0;
                    float h2 = acc[2] + b0, h3 = acc[3] + b0;
                    ep0 += h0 * h0; ep1 += h1 * h1;
                    ep2 += h2 * h2; ep3 += h3 * h3;
                }
                #pragma unroll
                for (int off = 1; off < 16; off <<= 1) {
                    ep0 += __shfl_xor(ep0, off);
                    ep1 += __shfl_xor(ep1, off);
                    ep2 += __shfl_xor(ep2, off);
                    ep3 += __shfl_xor(ep3, off);
                }
                if (li == 0) {
                    int s = m * 16 + lg * 4;
                    eparts[(s + 0) * 8 + wid] = ep0;
                    eparts[(s + 1) * 8 + wid] = ep1;
                    eparts[(s + 2) * 8 + wid] = ep2;
                    eparts[(s + 3) * 8 + wid] = ep3;
                }
            }
        }
        __syncthreads();

        // ---------- energy pooling argmax over 81 shifts ----------
        {
            float ev = -FLT_MAX; int ei = 0x7fffffff;
            if (tid < 81) {
                float e = 0.f;
                #pragma unroll
                for (int k = 0; k < 8; ++k) e += eparts[tid * 8 + k];
                ev = e; ei = tid;
            }
            #pragma unroll
            for (int off = 32; off; off >>= 1) {
                float v2 = __shfl_xor(ev, off);
                int   i2 = __shfl_xor(ei, off);
                argmaxStep(ev, ei, v2, i2);
            }
            if (lane == 0) { rv[wid] = ev; ri[wid] = ei; }
            __syncthreads();
            if (tid == 0) {
                float bv = rv[0]; int bi = ri[0];
                for (int k = 1; k < 8; ++k) argmaxStep(bv, bi, rv[k], ri[k]);
                hind_s = bi;
            }
            __syncthreads();
        }
        const int hind = hind_s;

        // ---------- recompute h[hind, c] in exact fp32 (80 FMAs) ----------
        float hv = bc;
        {
            const float* wp = encw + c;
            #pragma unroll 4
            for (int v = 80 - hind; v < 160 - hind; ++v)
                hv += wp[v * 512] * yap[v + hind];
        }
        if (iter > 0 && mprev) hv = 0.f;
        hrow[c] = hv;
        if (tid == 0) cnt = 0;
        __syncthreads();

        // ---------- exact top-64 by rank count ----------
        {
            const float k0 = hv * hv;
            int rank = 0;
            const float4* h4 = (const float4*)hrow;
            for (int q = 0; q < 128; ++q) {
                float4 hq = h4[q];
                int cb = q * 4;
                float ka = hq.x * hq.x, kb = hq.y * hq.y;
                float kc = hq.z * hq.z, kd = hq.w * hq.w;
                rank += (ka > k0) || (ka == k0 && (cb + 0) < c);
                rank += (kb > k0) || (kb == k0 && (cb + 1) < c);
                rank += (kc > k0) || (kc == k0 && (cb + 2) < c);
                rank += (kd > k0) || (kd == k0 && (cb + 3) < c);
            }
            bool sel = rank < 64;
            mprev = mprev || sel;
            if (sel) {
                int p = atomicAdd(&cnt, 1);
                selIdx[p] = c;
                selVal[p] = hv;
            }
        }
        __syncthreads();

        // ---------- sparse decoder: x_ext = h_sel @ dec_w + dec_b ----------
        if (tid < 160) {
            float a2 = decb[tid];
            for (int k = 0; k < 64; ++k)
                a2 += selVal[k] * decw[selIdx[k] * 160 + tid];
            xext[tid] = a2;
        }
        __syncthreads();

        // ---------- y_ele gather, loss, residual updates ----------
        float ye = 0.f, yrv = 0.f, lp = 0.f;
        if (tid < 80) {
            ye  = xext[80 - hind + tid];
            yrv = yr[tid];
            float d = ye - yrv;
            lp = (yy[tid] == 0.0f) ? 0.f : d * d;
        }
        {
            float ls = lp;
            #pragma unroll
            for (int off = 32; off; off >>= 1) ls += __shfl_xor(ls, off);
            if (lane == 0) rv[wid] = ls;
            __syncthreads();
            if (tid == 0) {
                float s = 0.f;
                for (int k = 0; k < 8; ++k) s += rv[k];
                blockLoss += (double)s;
            }
        }
        float xe = 0.f;
        if (tid < 80) xe = yap[tid + 159 - theta];
        __syncthreads();
        if (tid < 80) {
            yr[tid] = yrv - ye;
            xr[tid] -= xe;
        }
    }

    if (tid == 0) atomicAdd(lossSum, blockLoss);
}

__global__ void finish_kernel(const double* __restrict__ lossSum,
                              const int* __restrict__ nz,
                              float* __restrict__ out)
{
    int n = *nz;
    if (n < 1) n = 1;
    out[0] = (float)(*lossSum / (8.0 * (double)n));
}

extern "C" void kernel_launch(void* const* d_in, const int* in_sizes, int n_in,
                              void* d_out, int out_size, void* d_ws, size_t ws_size,
                              hipStream_t stream) {
    (void)in_sizes; (void)n_in; (void)out_size; (void)ws_size;
    const float* x    = (const float*)d_in[0];
    const float* y    = (const float*)d_in[1];
    const float* encw = (const float*)d_in[2];
    const float* encb = (const float*)d_in[3];
    const float* decw = (const float*)d_in[4];
    const float* decb = (const float*)d_in[5];

    unsigned short* whi = (unsigned short*)d_ws;                       // 512*160 bf16
    unsigned short* wlo = (unsigned short*)((char*)d_ws + 163840);     // 512*160 bf16
    double* lossSum = (double*)((char*)d_ws + 327680);
    int*    nz      = (int*)((char*)d_ws + 327688);

    hipMemsetAsync((char*)d_ws + 327680, 0, 16, stream);
    prep_kernel<<<320, 256, 0, stream>>>(encw, whi, wlo);
    mp_kernel<<<2048, 512, 0, stream>>>(x, y, encw, encb, decw, decb,
                                        whi, wlo, lossSum, nz);
    finish_kernel<<<1, 1, 0, stream>>>(lossSum, nz, (float*)d_out);
}